// Round 2
// baseline (725.556 us; speedup 1.0000x reference)
//
#include <hip/hip_runtime.h>
#include <math.h>

#define NRAY 8192
#define SSAMP 128
#define HD 256
#define AROW 264    // LDS row pitch in bf16
#define A1ROW 40    // layer1 A-tile pitch
#define FIXCAP 262144
#define FIXTHR 0.018f   // RNE 1-term tier: error margin ~= trunc tier @ 0.025

typedef short s16x8 __attribute__((ext_vector_type(8)));
typedef float f32x4 __attribute__((ext_vector_type(4)));

// ---------- bf16 helpers ----------
__device__ __forceinline__ unsigned short f2bf(float f) {      // RNE
    unsigned u = __float_as_uint(f);
    u += 0x7fffu + ((u >> 16) & 1u);
    return (unsigned short)(u >> 16);
}
__device__ __forceinline__ float bf2f(unsigned short s) {
    return __uint_as_float(((unsigned)s) << 16);
}
__device__ __forceinline__ void split2(float f, unsigned short& hi, unsigned short& lo) {
    unsigned u = __float_as_uint(f);
    hi = (unsigned short)(u >> 16);
    float r = f - __uint_as_float(u & 0xFFFF0000u);
    lo = f2bf(r);
}
// packed RNE f32->bf16x2 (gfx950 v_cvt_pk_bf16_f32): lo16 = bf16(a), hi16 = bf16(b)
__device__ __forceinline__ unsigned pack_bf16x2(float a, float b) {
    unsigned r;
    asm("v_cvt_pk_bf16_f32 %0, %1, %2" : "=v"(r) : "v"(a), "v"(b));
    return r;
}
// exact softplus (fixup / final tier)
__device__ __forceinline__ float softplus_fast(float x) {
    return fmaxf(x, 0.0f) + __logf(1.0f + __expf(-fabsf(x)));
}
// cheap softplus (1-term tier)
__device__ __forceinline__ float softplus_cheap(float x) {
    float m = __expf(-fabsf(x));
    float p = fmaf(m, fmaf(0.14258f, m, -0.44943f), 1.0f);
    return fmaxf(x, 0.0f) + m * p;
}
__device__ __forceinline__ float sigmoid_fast(float x) {
    return 1.0f / (1.0f + __expf(-x));
}

// ---------------- prep: pack W2/W3, pack layer1 B, cube intersection, zero counter ----------------
__global__ __launch_bounds__(256)
void prep_kernel(const float* __restrict__ W1, const float* __restrict__ b1,
                 const float* __restrict__ W2, const float* __restrict__ W3,
                 const float* __restrict__ ray0, const float* __restrict__ rdg,
                 unsigned short* __restrict__ P2, unsigned short* __restrict__ P3,
                 unsigned short* __restrict__ B1, float* __restrict__ rayinfo,
                 int* __restrict__ fix_cnt) {
    const int b = blockIdx.x, tid = threadIdx.x;
    if (b < 256) {
        int idx = b * 256 + tid;   // 0..65535
        int k = idx >> 8, n = idx & 255;
        int nt = n >> 4, kt = k >> 5, lq = (k >> 3) & 3, j = k & 7;
        int lane = (lq << 4) | (n & 15);
        size_t off = (size_t)((nt * 8 + kt) * 2) * 512 + (size_t)lane * 8 + j;
        float w = W2[idx];
        unsigned short hi = f2bf(w);
        P2[off] = hi; P2[off + 512] = f2bf(w - bf2f(hi));
        w = W3[idx];
        hi = f2bf(w);
        P3[off] = hi; P3[off + 512] = f2bf(w - bf2f(hi));
    } else if (b < 288) {
        int idx = (b - 256) * 256 + tid;   // 0..8191
        int w = idx & 511;
        int lane = w >> 3, j = w & 7;
        int k = ((lane >> 4) << 3) + j;
        int n = ((idx >> 9) << 4) + (lane & 15);
        unsigned short s = 0;
        if (k < 3) s = f2bf(W1[k * HD + n]);
        else if (k == 3) s = f2bf(b1[n]);
        else if (k < 7) s = f2bf(W1[(k - 4) * HD + n]);
        else if (k == 7) { unsigned short bh = f2bf(b1[n]); s = f2bf(b1[n] - bf2f(bh)); }
        else if (k < 11) { float wv = W1[(k - 8) * HD + n]; unsigned short wh = f2bf(wv); s = f2bf(wv - bf2f(wh)); }
        B1[idx] = s;
    } else {
        int r = (b - 288) * 256 + tid;     // 0..8191
        if (r == 0) *fix_cnt = 0;
        float o0 = ray0[3 * r], o1 = ray0[3 * r + 1], o2 = ray0[3 * r + 2];
        float v0 = rdg[3 * r], v1 = rdg[3 * r + 1], v2 = rdg[3 * r + 2];
        const float pd = 0.55f, lim = pd + 1e-6f;
        float di[6]; int insk[6]; int cnt = 0;
        for (int k = 0; k < 6; k++) {
            int a = k % 3;
            float pl = (k < 3) ? pd : -pd;
            float den = (a == 0) ? v0 : ((a == 1) ? v1 : v2);
            if (fabsf(den) < 1e-9f) den = 1e-9f;
            float oa = (a == 0) ? o0 : ((a == 1) ? o1 : o2);
            float dd = (pl - oa) / den;
            float px = o0 + dd * v0, py = o1 + dd * v1, pz = o2 + dd * v2;
            int ins = (fabsf(px) <= lim) && (fabsf(py) <= lim) && (fabsf(pz) <= lim);
            di[k] = dd; insk[k] = ins; cnt += ins;
        }
        float d0 = 0.f, sl = 2.4f;
        if (cnt == 2) {
            int k1 = -1, k2 = -1;
            for (int k = 0; k < 6; k++) if (insk[k]) { if (k1 < 0) k1 = k; else k2 = k; }
            float nrd = sqrtf(v0 * v0 + v1 * v1 + v2 * v2);
            float ax = di[k1] * v0, ay = di[k1] * v1, az = di[k1] * v2;
            float d1n = sqrtf(ax * ax + ay * ay + az * az) / nrd;
            float bx = di[k2] * v0, by = di[k2] * v1, bz = di[k2] * v2;
            float d2n = sqrtf(bx * bx + by * by + bz * bz) / nrd;
            d0 = fminf(d1n, d2n);
            sl = fmaxf(d1n, d2n) - d0;
        }
        float* ri = rayinfo + (size_t)r * 8;
        ri[0] = d0; ri[1] = sl;
        ri[2] = o0; ri[3] = o1; ri[4] = o2;
        ri[5] = v0; ri[6] = v1; ri[7] = v2;
    }
}

// ============ All GEMMs are operand-SWAPPED: D = W^T * Act^T ============
// C layout: col(lane&15)=sample, row((lane>>4)*4+reg)=channel -> each lane's 4 regs are
// 4 consecutive channels of one sample -> packed uint2 epilogue stores, float4 bias/W4.
// NT = number of 16-channel output chunks per wave (4 for 4-wave blocks, 2 for 8-wave).

// ---------- layer1 GEMM: one K=32 tile, acc = B1^T @ A1^T (bias folded in) ----------
template<int MT, int NT>
__device__ __forceinline__ void gemm_l1(const unsigned short* A1,
                                        const unsigned short* __restrict__ B1,
                                        f32x4 acc[MT][NT], int lane, int ntbase) {
    const int r15 = lane & 15, q = lane >> 4;
    s16x8 wh[NT];
#pragma unroll
    for (int nt = 0; nt < NT; nt++)
        wh[nt] = *(((const s16x8*)B1) + (size_t)(ntbase + nt) * 64 + lane);
#pragma unroll
    for (int mt = 0; mt < MT; mt++) {
        s16x8 ah = *(const s16x8*)(A1 + (mt * 16 + r15) * A1ROW + q * 8);
#pragma unroll
        for (int nt = 0; nt < NT; nt++)
            acc[mt][nt] = __builtin_amdgcn_mfma_f32_16x16x32_bf16(wh[nt], ah, (f32x4){0.f,0.f,0.f,0.f}, 0, 0, 0);
    }
}

// ---------- 1-term bf16 GEMM: acc += Wh^T * Ah^T ----------
template<int MT, int NT>
__device__ __forceinline__ void gemm_1t(const unsigned short* Act,
                                        const unsigned short* __restrict__ Wp,
                                        f32x4 acc[MT][NT], int lane, int ntbase) {
#pragma unroll
    for (int mt = 0; mt < MT; mt++)
#pragma unroll
        for (int nt = 0; nt < NT; nt++) acc[mt][nt] = (f32x4){0.f, 0.f, 0.f, 0.f};
    const int r15 = lane & 15, q = lane >> 4;
#pragma unroll 2
    for (int kt = 0; kt < 8; kt++) {
        s16x8 wh[NT];
#pragma unroll
        for (int nt = 0; nt < NT; nt++) {
            const s16x8* wp = ((const s16x8*)Wp) + (size_t)((ntbase + nt) * 8 + kt) * 128 + lane;
            wh[nt] = wp[0];
        }
        const int kc = kt * 32 + q * 8;
#pragma unroll
        for (int mt = 0; mt < MT; mt++) {
            s16x8 ah = *(const s16x8*)(Act + (mt * 16 + r15) * AROW + kc);
#pragma unroll
            for (int nt = 0; nt < NT; nt++)
                acc[mt][nt] = __builtin_amdgcn_mfma_f32_16x16x32_bf16(wh[nt], ah, acc[mt][nt], 0, 0, 0);
        }
    }
}

// ---------- 3-term split GEMM (fixup tier): Wh*Ah + Wh*Al + Wl*Ah ----------
template<int MT, int NT>
__device__ __forceinline__ void gemm_3t(const unsigned short* Ahi, const unsigned short* Alo,
                                        const unsigned short* __restrict__ Wp,
                                        f32x4 acc[MT][NT], int lane, int ntbase) {
#pragma unroll
    for (int mt = 0; mt < MT; mt++)
#pragma unroll
        for (int nt = 0; nt < NT; nt++) acc[mt][nt] = (f32x4){0.f, 0.f, 0.f, 0.f};
    const int r15 = lane & 15, q = lane >> 4;
#pragma unroll 2
    for (int kt = 0; kt < 8; kt++) {
        s16x8 wh[NT], wl[NT];
#pragma unroll
        for (int nt = 0; nt < NT; nt++) {
            const s16x8* wp = ((const s16x8*)Wp) + (size_t)((ntbase + nt) * 8 + kt) * 128 + lane;
            wh[nt] = wp[0];
            wl[nt] = wp[64];
        }
        const int kc = kt * 32 + q * 8;
#pragma unroll
        for (int mt = 0; mt < MT; mt++) {
            s16x8 ah = *(const s16x8*)(Ahi + (mt * 16 + r15) * AROW + kc);
            s16x8 al = *(const s16x8*)(Alo + (mt * 16 + r15) * AROW + kc);
#pragma unroll
            for (int nt = 0; nt < NT; nt++) {
                acc[mt][nt] = __builtin_amdgcn_mfma_f32_16x16x32_bf16(wh[nt], ah, acc[mt][nt], 0, 0, 0);
                acc[mt][nt] = __builtin_amdgcn_mfma_f32_16x16x32_bf16(wl[nt], ah, acc[mt][nt], 0, 0, 0);
                acc[mt][nt] = __builtin_amdgcn_mfma_f32_16x16x32_bf16(wh[nt], al, acc[mt][nt], 0, 0, 0);
            }
        }
    }
}

// dual (value + tangent) 3-term variant — final tier
template<int MT, int NT>
__device__ __forceinline__ void gemm_dual(const unsigned short* Avh, const unsigned short* Avl,
                                          const unsigned short* Ath, const unsigned short* Atl,
                                          const unsigned short* __restrict__ Wp,
                                          f32x4 av[MT][NT], f32x4 at[MT][NT], int lane, int ntbase) {
#pragma unroll
    for (int mt = 0; mt < MT; mt++)
#pragma unroll
        for (int nt = 0; nt < NT; nt++) {
            av[mt][nt] = (f32x4){0.f, 0.f, 0.f, 0.f};
            at[mt][nt] = (f32x4){0.f, 0.f, 0.f, 0.f};
        }
    const int r15 = lane & 15, q = lane >> 4;
#pragma unroll 2
    for (int kt = 0; kt < 8; kt++) {
        s16x8 wh[NT], wl[NT];
#pragma unroll
        for (int nt = 0; nt < NT; nt++) {
            const s16x8* wp = ((const s16x8*)Wp) + (size_t)((ntbase + nt) * 8 + kt) * 128 + lane;
            wh[nt] = wp[0];
            wl[nt] = wp[64];
        }
        const int kc = kt * 32 + q * 8;
#pragma unroll
        for (int mt = 0; mt < MT; mt++) {
            s16x8 avhf = *(const s16x8*)(Avh + (mt * 16 + r15) * AROW + kc);
            s16x8 avlf = *(const s16x8*)(Avl + (mt * 16 + r15) * AROW + kc);
            s16x8 athf = *(const s16x8*)(Ath + (mt * 16 + r15) * AROW + kc);
            s16x8 atlf = *(const s16x8*)(Atl + (mt * 16 + r15) * AROW + kc);
#pragma unroll
            for (int nt = 0; nt < NT; nt++) {
                av[mt][nt] = __builtin_amdgcn_mfma_f32_16x16x32_bf16(wh[nt], avhf, av[mt][nt], 0, 0, 0);
                av[mt][nt] = __builtin_amdgcn_mfma_f32_16x16x32_bf16(wl[nt], avhf, av[mt][nt], 0, 0, 0);
                av[mt][nt] = __builtin_amdgcn_mfma_f32_16x16x32_bf16(wh[nt], avlf, av[mt][nt], 0, 0, 0);
                at[mt][nt] = __builtin_amdgcn_mfma_f32_16x16x32_bf16(wh[nt], athf, at[mt][nt], 0, 0, 0);
                at[mt][nt] = __builtin_amdgcn_mfma_f32_16x16x32_bf16(wl[nt], athf, at[mt][nt], 0, 0, 0);
                at[mt][nt] = __builtin_amdgcn_mfma_f32_16x16x32_bf16(wh[nt], atlf, at[mt][nt], 0, 0, 0);
            }
        }
    }
}

// epilogue (layer1, bias folded): cheap softplus + packed RNE store (transposed layout)
template<int MT, int NT>
__device__ __forceinline__ void epi_l1(f32x4 acc[MT][NT], unsigned short* Ahi, int lane, int wn0) {
    const int r15 = lane & 15, q = lane >> 4;
#pragma unroll
    for (int mt = 0; mt < MT; mt++) {
        unsigned short* rowp = Ahi + (mt * 16 + r15) * AROW + wn0 + q * 4;
#pragma unroll
        for (int nt = 0; nt < NT; nt++) {
            float h0 = softplus_cheap(acc[mt][nt][0]);
            float h1 = softplus_cheap(acc[mt][nt][1]);
            float h2 = softplus_cheap(acc[mt][nt][2]);
            float h3 = softplus_cheap(acc[mt][nt][3]);
            *reinterpret_cast<uint2*>(rowp + nt * 16) =
                make_uint2(pack_bf16x2(h0, h1), pack_bf16x2(h2, h3));
        }
    }
}

// epilogue (layer1, bias folded): exact softplus + hi/lo split (fixup tier)
template<int MT, int NT>
__device__ __forceinline__ void epi_l1_sp(f32x4 acc[MT][NT], unsigned short* Ahi, unsigned short* Alo,
                                          int lane, int wn0) {
    const int r15 = lane & 15, q = lane >> 4;
#pragma unroll
    for (int mt = 0; mt < MT; mt++) {
        const int rowoff = (mt * 16 + r15) * AROW + wn0 + q * 4;
#pragma unroll
        for (int nt = 0; nt < NT; nt++) {
            float h0 = softplus_fast(acc[mt][nt][0]);
            float h1 = softplus_fast(acc[mt][nt][1]);
            float h2 = softplus_fast(acc[mt][nt][2]);
            float h3 = softplus_fast(acc[mt][nt][3]);
            unsigned x0 = pack_bf16x2(h0, h1), x1 = pack_bf16x2(h2, h3);
            float l0 = h0 - __uint_as_float(x0 << 16);
            float l1 = h1 - __uint_as_float(x0 & 0xFFFF0000u);
            float l2 = h2 - __uint_as_float(x1 << 16);
            float l3 = h3 - __uint_as_float(x1 & 0xFFFF0000u);
            *reinterpret_cast<uint2*>(Ahi + rowoff + nt * 16) = make_uint2(x0, x1);
            *reinterpret_cast<uint2*>(Alo + rowoff + nt * 16) =
                make_uint2(pack_bf16x2(l0, l1), pack_bf16x2(l2, l3));
        }
    }
}

// epilogue (1-term): cheap softplus + packed RNE store
template<int MT, int NT>
__device__ __forceinline__ void epi_hidden_1t(f32x4 acc[MT][NT], const float* __restrict__ b,
                                              unsigned short* Ahi, int lane, int wn0) {
    const int r15 = lane & 15, q = lane >> 4;
    f32x4 bb[NT];
#pragma unroll
    for (int nt = 0; nt < NT; nt++) bb[nt] = *(const f32x4*)(b + wn0 + nt * 16 + q * 4);
#pragma unroll
    for (int mt = 0; mt < MT; mt++) {
        unsigned short* rowp = Ahi + (mt * 16 + r15) * AROW + wn0 + q * 4;
#pragma unroll
        for (int nt = 0; nt < NT; nt++) {
            float h0 = softplus_cheap(acc[mt][nt][0] + bb[nt][0]);
            float h1 = softplus_cheap(acc[mt][nt][1] + bb[nt][1]);
            float h2 = softplus_cheap(acc[mt][nt][2] + bb[nt][2]);
            float h3 = softplus_cheap(acc[mt][nt][3] + bb[nt][3]);
            *reinterpret_cast<uint2*>(rowp + nt * 16) =
                make_uint2(pack_bf16x2(h0, h1), pack_bf16x2(h2, h3));
        }
    }
}

// epilogue (split hi/lo, fixup tier) — exact softplus
template<int MT, int NT>
__device__ __forceinline__ void epi_hidden_sp(f32x4 acc[MT][NT], const float* __restrict__ b,
                                              unsigned short* Ahi, unsigned short* Alo,
                                              int lane, int wn0) {
    const int r15 = lane & 15, q = lane >> 4;
    f32x4 bb[NT];
#pragma unroll
    for (int nt = 0; nt < NT; nt++) bb[nt] = *(const f32x4*)(b + wn0 + nt * 16 + q * 4);
#pragma unroll
    for (int mt = 0; mt < MT; mt++) {
        const int rowoff = (mt * 16 + r15) * AROW + wn0 + q * 4;
#pragma unroll
        for (int nt = 0; nt < NT; nt++) {
            float h0 = softplus_fast(acc[mt][nt][0] + bb[nt][0]);
            float h1 = softplus_fast(acc[mt][nt][1] + bb[nt][1]);
            float h2 = softplus_fast(acc[mt][nt][2] + bb[nt][2]);
            float h3 = softplus_fast(acc[mt][nt][3] + bb[nt][3]);
            unsigned x0 = pack_bf16x2(h0, h1), x1 = pack_bf16x2(h2, h3);
            float l0 = h0 - __uint_as_float(x0 << 16);
            float l1 = h1 - __uint_as_float(x0 & 0xFFFF0000u);
            float l2 = h2 - __uint_as_float(x1 << 16);
            float l3 = h3 - __uint_as_float(x1 & 0xFFFF0000u);
            *reinterpret_cast<uint2*>(Ahi + rowoff + nt * 16) = make_uint2(x0, x1);
            *reinterpret_cast<uint2*>(Alo + rowoff + nt * 16) =
                make_uint2(pack_bf16x2(l0, l1), pack_bf16x2(l2, l3));
        }
    }
}

template<int MT, int NT>
__device__ __forceinline__ void epi_dual(f32x4 av[MT][NT], f32x4 at[MT][NT], const float* __restrict__ b,
                                         unsigned short* Avh, unsigned short* Avl,
                                         unsigned short* Ath, unsigned short* Atl,
                                         int lane, int wn0) {
    const int r15 = lane & 15, q = lane >> 4;
    f32x4 bb[NT];
#pragma unroll
    for (int nt = 0; nt < NT; nt++) bb[nt] = *(const f32x4*)(b + wn0 + nt * 16 + q * 4);
#pragma unroll
    for (int mt = 0; mt < MT; mt++) {
        const int rowoff = (mt * 16 + r15) * AROW + wn0 + q * 4;
#pragma unroll
        for (int nt = 0; nt < NT; nt++) {
            float h[4], g[4];
#pragma unroll
            for (int r = 0; r < 4; r++) {
                float z = av[mt][nt][r] + bb[nt][r];
                h[r] = softplus_fast(z);
                g[r] = sigmoid_fast(z) * at[mt][nt][r];
            }
            unsigned x0 = pack_bf16x2(h[0], h[1]), x1 = pack_bf16x2(h[2], h[3]);
            float l0 = h[0] - __uint_as_float(x0 << 16);
            float l1 = h[1] - __uint_as_float(x0 & 0xFFFF0000u);
            float l2 = h[2] - __uint_as_float(x1 << 16);
            float l3 = h[3] - __uint_as_float(x1 & 0xFFFF0000u);
            *reinterpret_cast<uint2*>(Avh + rowoff + nt * 16) = make_uint2(x0, x1);
            *reinterpret_cast<uint2*>(Avl + rowoff + nt * 16) =
                make_uint2(pack_bf16x2(l0, l1), pack_bf16x2(l2, l3));
            x0 = pack_bf16x2(g[0], g[1]); x1 = pack_bf16x2(g[2], g[3]);
            l0 = g[0] - __uint_as_float(x0 << 16);
            l1 = g[1] - __uint_as_float(x0 & 0xFFFF0000u);
            l2 = g[2] - __uint_as_float(x1 << 16);
            l3 = g[3] - __uint_as_float(x1 & 0xFFFF0000u);
            *reinterpret_cast<uint2*>(Ath + rowoff + nt * 16) = make_uint2(x0, x1);
            *reinterpret_cast<uint2*>(Atl + rowoff + nt * 16) =
                make_uint2(pack_bf16x2(l0, l1), pack_bf16x2(l2, l3));
        }
    }
}

// layer3 activation + W4 dot (transposed): lane-local dot over 4*NT channels, 2 shuffles
template<int MT, int NT, bool CH>
__device__ __forceinline__ void l4_reduce(f32x4 acc[MT][NT], const float* __restrict__ b3,
                                          const float* __restrict__ W4,
                                          float* partial, int lane, int wn0) {
    const int r15 = lane & 15, q = lane >> 4;
    f32x4 w4v[NT], b3v[NT];
#pragma unroll
    for (int nt = 0; nt < NT; nt++) {
        w4v[nt] = *(const f32x4*)(W4 + wn0 + nt * 16 + q * 4);
        b3v[nt] = *(const f32x4*)(b3 + wn0 + nt * 16 + q * 4);
    }
#pragma unroll
    for (int mt = 0; mt < MT; mt++) {
        float p = 0.f;
#pragma unroll
        for (int nt = 0; nt < NT; nt++)
#pragma unroll
            for (int r = 0; r < 4; r++) {
                float z = acc[mt][nt][r] + b3v[nt][r];
                float h = CH ? softplus_cheap(z) : softplus_fast(z);
                p = fmaf(h, w4v[nt][r], p);
            }
        p += __shfl_xor(p, 16, 64);
        p += __shfl_xor(p, 32, 64);
        if (q == 0) partial[mt * 16 + r15] = p;
    }
}

template<int MT, int NT>
__device__ __forceinline__ void l4_reduce_dual(f32x4 av[MT][NT], f32x4 at[MT][NT],
                                               const float* __restrict__ b3, const float* __restrict__ W4,
                                               float* pv, float* pt, int lane, int wn0) {
    const int r15 = lane & 15, q = lane >> 4;
    f32x4 w4v[NT], b3v[NT];
#pragma unroll
    for (int nt = 0; nt < NT; nt++) {
        w4v[nt] = *(const f32x4*)(W4 + wn0 + nt * 16 + q * 4);
        b3v[nt] = *(const f32x4*)(b3 + wn0 + nt * 16 + q * 4);
    }
#pragma unroll
    for (int mt = 0; mt < MT; mt++) {
        float sv = 0.f, st = 0.f;
#pragma unroll
        for (int nt = 0; nt < NT; nt++)
#pragma unroll
            for (int r = 0; r < 4; r++) {
                float z = av[mt][nt][r] + b3v[nt][r];
                sv = fmaf(softplus_fast(z), w4v[nt][r], sv);
                st = fmaf(sigmoid_fast(z) * at[mt][nt][r], w4v[nt][r], st);
            }
        sv += __shfl_xor(sv, 16, 64);
        sv += __shfl_xor(sv, 32, 64);
        st += __shfl_xor(st, 16, 64);
        st += __shfl_xor(st, 32, 64);
        if (q == 0) {
            pv[mt * 16 + r15] = sv;
            pt[mt * 16 + r15] = st;
        }
    }
}

// ---------------- coarse: block = (ray, half), 64 samples, 8 waves (NT=2) ----------------
// 512 threads / 8 waves: acc[4][2] = 32 AGPR per wave (was 64) so 3-4 blocks (24-32
// waves) fit per CU instead of 2 (16 waves) -> latency hiding. LDS unchanged (4 blk/CU).
__global__ __launch_bounds__(512, 6)
void coarse_mfma(const float* __restrict__ rayinfo,
                 const unsigned short* __restrict__ B1,
                 const unsigned short* __restrict__ P2, const float* __restrict__ b2,
                 const unsigned short* __restrict__ P3, const float* __restrict__ b3,
                 const float* __restrict__ W4, const float* __restrict__ b4,
                 float* __restrict__ val_out, float* __restrict__ dprop_out,
                 int* __restrict__ fix_cnt, int* __restrict__ fix_list) {
    __shared__ __align__(16) unsigned short Ahi[64 * AROW];
    __shared__ __align__(16) unsigned short A1[64 * A1ROW];
    float* partial = (float*)A1;    // 8*64 floats = 2048B <= 5120B, used after l1 done
    const int tid = threadIdx.x;
    const int lane = tid & 63, wave = tid >> 6;   // wave 0..7
    const int r = blockIdx.x >> 1, half = blockIdx.x & 1;

    if (tid < 64) {
        const float* ri = rayinfo + (size_t)r * 8;
        const int s = half * 64 + tid;
        float t = (float)s * (1.0f / 127.0f);
        float d = fmaf(t, ri[1], ri[0]);
        dprop_out[r * SSAMP + s] = d;
        float px = fmaf(d, ri[5], ri[2]);
        float py = fmaf(d, ri[6], ri[3]);
        float pz = fmaf(d, ri[7], ri[4]);
        unsigned short hx, lx, hy, ly, hz, lz;
        split2(px, hx, lx); split2(py, hy, ly); split2(pz, hz, lz);
        unsigned short* row = A1 + tid * A1ROW;
        row[0] = hx; row[1] = hy; row[2] = hz; row[3] = 0x3F80u;
        row[4] = lx; row[5] = ly; row[6] = lz; row[7] = 0x3F80u;
        row[8] = hx; row[9] = hy; row[10] = hz;
#pragma unroll
        for (int c = 11; c < 32; c++) row[c] = 0;
    }
    __syncthreads();
    f32x4 acc[4][2];
    gemm_l1<4, 2>(A1, B1, acc, lane, wave * 2);
    epi_l1<4, 2>(acc, Ahi, lane, wave * 32);
    __syncthreads();
    gemm_1t<4, 2>(Ahi, P2, acc, lane, wave * 2);
    __syncthreads();
    epi_hidden_1t<4, 2>(acc, b2, Ahi, lane, wave * 32);
    __syncthreads();
    gemm_1t<4, 2>(Ahi, P3, acc, lane, wave * 2);
    l4_reduce<4, 2, true>(acc, b3, W4, &partial[wave * 64], lane, wave * 32);
    __syncthreads();
    if (tid < 64) {
        float v = b4[0];
#pragma unroll
        for (int w = 0; w < 8; w++) v += partial[w * 64 + tid];
        int idx = r * SSAMP + half * 64 + tid;
        val_out[idx] = v;
        if (fabsf(v) < FIXTHR) {
            int pos = atomicAdd(fix_cnt, 1);
            if (pos < FIXCAP) fix_list[pos] = idx;
        }
    }
}

// ---------------- fixup (32-sample 3-term MFMA batches, MFMA layer1, 4 blocks/CU) ----------------
__global__ __launch_bounds__(256, 4)
void fixup3_mfma(const int* __restrict__ counter, const int* __restrict__ list,
                 float* __restrict__ val, const float* __restrict__ dprop,
                 const float* __restrict__ ray0, const float* __restrict__ rdg,
                 const unsigned short* __restrict__ B1,
                 const unsigned short* __restrict__ P2, const float* __restrict__ b2,
                 const unsigned short* __restrict__ P3, const float* __restrict__ b3,
                 const float* __restrict__ W4, const float* __restrict__ b4) {
    __shared__ __align__(16) unsigned short Ahi[32 * AROW];
    __shared__ __align__(16) unsigned short Alo[32 * AROW];
    __shared__ __align__(16) unsigned short A1[32 * A1ROW];
    __shared__ float partial[4][32];
    __shared__ int bidxs[32];
    const int cnt = min(*counter, FIXCAP);
    const int base = blockIdx.x * 32;
    if (base >= cnt) return;
    const int tid = threadIdx.x;
    const int lane = tid & 63, wave = tid >> 6;
    if (tid < 32) {
        const int i = min(base + tid, cnt - 1);   // tail clamp: duplicates write same value
        const int bidx = list[i];
        bidxs[tid] = bidx;
        const int rr = bidx >> 7;                 // r-major: idx = r*SSAMP + s
        float d = dprop[bidx];
        float px = ray0[3 * rr] + d * rdg[3 * rr];
        float py = ray0[3 * rr + 1] + d * rdg[3 * rr + 1];
        float pz = ray0[3 * rr + 2] + d * rdg[3 * rr + 2];
        unsigned short hx, lx, hy, ly, hz, lz;
        split2(px, hx, lx); split2(py, hy, ly); split2(pz, hz, lz);
        unsigned short* row = A1 + tid * A1ROW;
        row[0] = hx; row[1] = hy; row[2] = hz; row[3] = 0x3F80u;
        row[4] = lx; row[5] = ly; row[6] = lz; row[7] = 0x3F80u;
        row[8] = hx; row[9] = hy; row[10] = hz;
#pragma unroll
        for (int c = 11; c < 32; c++) row[c] = 0;
    }
    __syncthreads();
    f32x4 acc[2][4];
    gemm_l1<2, 4>(A1, B1, acc, lane, wave * 4);
    epi_l1_sp<2, 4>(acc, Ahi, Alo, lane, wave * 64);
    __syncthreads();
    gemm_3t<2, 4>(Ahi, Alo, P2, acc, lane, wave * 4);
    __syncthreads();
    epi_hidden_sp<2, 4>(acc, b2, Ahi, Alo, lane, wave * 64);
    __syncthreads();
    gemm_3t<2, 4>(Ahi, Alo, P3, acc, lane, wave * 4);
    l4_reduce<2, 4, false>(acc, b3, W4, &partial[wave][0], lane, wave * 64);
    __syncthreads();
    if (tid < 32) {
        float v = partial[0][tid] + partial[1][tid] + partial[2][tid] + partial[3][tid] + b4[0];
        val[bidxs[tid]] = v;
    }
}

// ---------------- refine: scan + 8-iter secant + final dual, all in one (16 rays/block) ----------------
__global__ __launch_bounds__(256, 4)
void refine_mfma(const float* __restrict__ val, const float* __restrict__ dprop,
                 const float* __restrict__ ray0, const float* __restrict__ rdg,
                 const float* __restrict__ W1, const float* __restrict__ b1,
                 const unsigned short* __restrict__ P2, const float* __restrict__ b2,
                 const unsigned short* __restrict__ P3, const float* __restrict__ b3,
                 const float* __restrict__ W4, const float* __restrict__ b4,
                 float* __restrict__ out) {
    __shared__ __align__(16) unsigned short Avh[16 * AROW];
    __shared__ __align__(16) unsigned short Avl[16 * AROW];
    __shared__ __align__(16) unsigned short Ath[16 * AROW];
    __shared__ __align__(16) unsigned short Atl[16 * AROW];
    __shared__ float partial[4][16], ptan[4][16];
    __shared__ float dl[16], fl[16], dh[16], fh[16], dps[16];
    __shared__ int mks[16];
    unsigned short* Ahi = Avh;   // secant reuses plane 0
    const int tid = threadIdx.x;
    const int lane = tid & 63, wave = tid >> 6;
    const int r0 = blockIdx.x * 16;

    // ---- scan: wave w handles rays r0+w*4 .. +3 ----
    for (int i = 0; i < 4; i++) {
        const int r = r0 + wave * 4 + i;
        const float2 v = *(const float2*)(val + (size_t)r * SSAMP + lane * 2);
        const float2 dd = *(const float2*)(dprop + (size_t)r * SSAMP + lane * 2);
        float vnext = __shfl_down(v.x, 1, 64);
        const int s0 = lane * 2, s1 = s0 + 1;
        float pr0 = v.x * v.y;
        int sg0 = (pr0 > 0.f) ? 1 : ((pr0 < 0.f) ? -1 : 0);
        int k0 = (sg0 * (SSAMP - s0) + 129) * 256 + s0;
        int k1;
        if (lane == 63) {
            k1 = (1 + 129) * 256 + 127;          // appended cost[127] = 1
        } else {
            float pr1 = v.y * vnext;
            int sg1 = (pr1 > 0.f) ? 1 : ((pr1 < 0.f) ? -1 : 0);
            k1 = (sg1 * (SSAMP - s1) + 129) * 256 + s1;
        }
        int k = min(k0, k1);
#pragma unroll
        for (int m = 1; m < 64; m <<= 1) k = min(k, __shfl_xor(k, m, 64));
        int bidx = k & 255;
        int cmin = (k >> 8) - 129;
        int idxh = min(bidx + 1, SSAMP - 1);
        int ow = bidx >> 1, oh = idxh >> 1;
        float fa = __shfl(v.x, ow, 64), fb = __shfl(v.y, ow, 64);
        float da = __shfl(dd.x, ow, 64), db = __shfl(dd.y, ow, 64);
        float fa2 = __shfl(v.x, oh, 64), fb2 = __shfl(v.y, oh, 64);
        float da2 = __shfl(dd.x, oh, 64), db2 = __shfl(dd.y, oh, 64);
        float v0 = __shfl(v.x, 0, 64);
        if (lane == 0) {
            float f_low = (bidx & 1) ? fb : fa;
            float d_low = (bidx & 1) ? db : da;
            float f_high = (idxh & 1) ? fb2 : fa2;
            float d_high = (idxh & 1) ? db2 : da2;
            int sl = wave * 4 + i;
            mks[sl] = (cmin < 0) && (f_low < 0.f) && (v0 < 0.f);
            float den = f_high - f_low;
            if (fabsf(den) < 1e-12f) den = 1e-12f;
            dl[sl] = d_low; fl[sl] = f_low; dh[sl] = d_high; fh[sl] = f_high;
            dps[sl] = -f_low * (d_high - d_low) / den + d_low;
        }
    }
    __syncthreads();
    // ---- 8 secant iterations (1-term, cheap softplus) ----
    for (int it = 0; it < 8; it++) {
        {
            const int pt = tid >> 4, jb = (tid & 15) << 4;
            const int rr = r0 + pt;
            float d = dps[pt];
            float px = ray0[3 * rr] + d * rdg[3 * rr];
            float py = ray0[3 * rr + 1] + d * rdg[3 * rr + 1];
            float pz = ray0[3 * rr + 2] + d * rdg[3 * rr + 2];
            for (int j = jb; j < jb + 16; j += 4) {
                float4 wa = *(const float4*)(W1 + j);
                float4 wb = *(const float4*)(W1 + 256 + j);
                float4 wc = *(const float4*)(W1 + 512 + j);
                float4 bb = *(const float4*)(b1 + j);
                float z[4];
                z[0] = fmaf(px, wa.x, fmaf(py, wb.x, fmaf(pz, wc.x, bb.x)));
                z[1] = fmaf(px, wa.y, fmaf(py, wb.y, fmaf(pz, wc.y, bb.y)));
                z[2] = fmaf(px, wa.z, fmaf(py, wb.z, fmaf(pz, wc.z, bb.z)));
                z[3] = fmaf(px, wa.w, fmaf(py, wb.w, fmaf(pz, wc.w, bb.w)));
                *reinterpret_cast<uint2*>(&Ahi[pt * AROW + j]) =
                    make_uint2(pack_bf16x2(softplus_cheap(z[0]), softplus_cheap(z[1])),
                               pack_bf16x2(softplus_cheap(z[2]), softplus_cheap(z[3])));
            }
        }
        __syncthreads();
        f32x4 acc[1][4];
        gemm_1t<1, 4>(Ahi, P2, acc, lane, wave * 4);
        __syncthreads();
        epi_hidden_1t<1, 4>(acc, b2, Ahi, lane, wave * 64);
        __syncthreads();
        gemm_1t<1, 4>(Ahi, P3, acc, lane, wave * 4);
        l4_reduce<1, 4, true>(acc, b3, W4, &partial[wave][0], lane, wave * 64);
        __syncthreads();
        if (tid < 16) {
            float fm = partial[0][tid] + partial[1][tid] + partial[2][tid] + partial[3][tid] + b4[0];
            float dpv = dps[tid];
            float dlv = dl[tid], flv = fl[tid], dhv = dh[tid], fhv = fh[tid];
            if (fm < 0.f) { dlv = dpv; flv = fm; } else { dhv = dpv; fhv = fm; }
            float den = fhv - flv;
            if (fabsf(den) < 1e-12f) den = 1e-12f;
            dps[tid] = -flv * (dhv - dlv) / den + dlv;
            dl[tid] = dlv; fl[tid] = flv; dh[tid] = dhv; fh[tid] = fhv;
        }
        __syncthreads();
    }
    // ---- final: dual-number 3-term eval + implicit correction ----
    {
        const int pt = tid >> 4, jb = (tid & 15) << 4;
        const int rr = r0 + pt;
        float d = dps[pt];
        float v0 = rdg[3 * rr], v1 = rdg[3 * rr + 1], v2 = rdg[3 * rr + 2];
        float px = ray0[3 * rr] + d * v0;
        float py = ray0[3 * rr + 1] + d * v1;
        float pz = ray0[3 * rr + 2] + d * v2;
        for (int j = jb; j < jb + 16; j += 4) {
            float4 wa = *(const float4*)(W1 + j);
            float4 wb = *(const float4*)(W1 + 256 + j);
            float4 wc = *(const float4*)(W1 + 512 + j);
            float4 bb = *(const float4*)(b1 + j);
            float z[4], zt[4], h[4], g[4];
            z[0] = fmaf(px, wa.x, fmaf(py, wb.x, fmaf(pz, wc.x, bb.x)));
            z[1] = fmaf(px, wa.y, fmaf(py, wb.y, fmaf(pz, wc.y, bb.y)));
            z[2] = fmaf(px, wa.z, fmaf(py, wb.z, fmaf(pz, wc.z, bb.z)));
            z[3] = fmaf(px, wa.w, fmaf(py, wb.w, fmaf(pz, wc.w, bb.w)));
            zt[0] = fmaf(v0, wa.x, fmaf(v1, wb.x, v2 * wc.x));
            zt[1] = fmaf(v0, wa.y, fmaf(v1, wb.y, v2 * wc.y));
            zt[2] = fmaf(v0, wa.z, fmaf(v1, wb.z, v2 * wc.z));
            zt[3] = fmaf(v0, wa.w, fmaf(v1, wb.w, v2 * wc.w));
#pragma unroll
            for (int i = 0; i < 4; i++) {
                h[i] = softplus_fast(z[i]);
                g[i] = sigmoid_fast(z[i]) * zt[i];
            }
            unsigned x0 = pack_bf16x2(h[0], h[1]), x1 = pack_bf16x2(h[2], h[3]);
            float l0 = h[0] - __uint_as_float(x0 << 16);
            float l1 = h[1] - __uint_as_float(x0 & 0xFFFF0000u);
            float l2 = h[2] - __uint_as_float(x1 << 16);
            float l3 = h[3] - __uint_as_float(x1 & 0xFFFF0000u);
            *reinterpret_cast<uint2*>(&Avh[pt * AROW + j]) = make_uint2(x0, x1);
            *reinterpret_cast<uint2*>(&Avl[pt * AROW + j]) =
                make_uint2(pack_bf16x2(l0, l1), pack_bf16x2(l2, l3));
            x0 = pack_bf16x2(g[0], g[1]); x1 = pack_bf16x2(g[2], g[3]);
            l0 = g[0] - __uint_as_float(x0 << 16);
            l1 = g[1] - __uint_as_float(x0 & 0xFFFF0000u);
            l2 = g[2] - __uint_as_float(x1 << 16);
            l3 = g[3] - __uint_as_float(x1 & 0xFFFF0000u);
            *reinterpret_cast<uint2*>(&Ath[pt * AROW + j]) = make_uint2(x0, x1);
            *reinterpret_cast<uint2*>(&Atl[pt * AROW + j]) =
                make_uint2(pack_bf16x2(l0, l1), pack_bf16x2(l2, l3));
        }
    }
    __syncthreads();
    f32x4 av[1][4], at[1][4];
    gemm_dual<1, 4>(Avh, Avl, Ath, Atl, P2, av, at, lane, wave * 4);
    __syncthreads();
    epi_dual<1, 4>(av, at, b2, Avh, Avl, Ath, Atl, lane, wave * 64);
    __syncthreads();
    gemm_dual<1, 4>(Avh, Avl, Ath, Atl, P3, av, at, lane, wave * 4);
    l4_reduce_dual<1, 4>(av, at, b3, W4, &partial[wave][0], &ptan[wave][0], lane, wave * 64);
    __syncthreads();
    if (tid < 16) {
        float f = partial[0][tid] + partial[1][tid] + partial[2][tid] + partial[3][tid] + b4[0];
        float ft = ptan[0][tid] + ptan[1][tid] + ptan[2][tid] + ptan[3][tid];
        if (fabsf(ft) < 1e-6f) ft = (ft < 0.f) ? -1e-6f : 1e-6f;
        float dres = dps[tid] - f / ft;
        out[r0 + tid] = mks[tid] ? dres : 0.0f;
    }
}

extern "C" void kernel_launch(void* const* d_in, const int* in_sizes, int n_in,
                              void* d_out, int out_size, void* d_ws, size_t ws_size,
                              hipStream_t stream) {
    const float* ray0 = (const float*)d_in[0];
    const float* rdg  = (const float*)d_in[1];
    const float* W1 = (const float*)d_in[2];
    const float* b1 = (const float*)d_in[3];
    const float* W2 = (const float*)d_in[4];
    const float* b2 = (const float*)d_in[5];
    const float* W3 = (const float*)d_in[6];
    const float* b3 = (const float*)d_in[7];
    const float* W4 = (const float*)d_in[8];
    const float* b4 = (const float*)d_in[9];
    float* out = (float*)d_out;

    float* ws = (float*)d_ws;
    float* val    = ws;                                 // SSAMP*NRAY, r-major [r][s]
    float* dprop  = ws + (size_t)SSAMP * NRAY;          // r-major [r][s]
    unsigned short* P2 = (unsigned short*)(ws + (size_t)2 * SSAMP * NRAY);
    unsigned short* P3 = P2 + 131072;
    unsigned short* B1 = P3 + 131072;       // 8192 shorts
    float* rayinfo = (float*)(B1 + 8192);   // NRAY*8 floats
    int* fix_cnt  = (int*)(rayinfo + (size_t)NRAY * 8);
    int* fix_list = fix_cnt + 64;           // FIXCAP ints

    hipLaunchKernelGGL(prep_kernel, dim3(320), dim3(256), 0, stream,
                       W1, b1, W2, W3, ray0, rdg, P2, P3, B1, rayinfo, fix_cnt);
    hipLaunchKernelGGL(coarse_mfma, dim3(NRAY * 2), dim3(512), 0, stream,
                       rayinfo, B1, P2, b2, P3, b3, W4, b4, val, dprop, fix_cnt, fix_list);
    hipLaunchKernelGGL(fixup3_mfma, dim3(FIXCAP / 32), dim3(256), 0, stream,
                       fix_cnt, fix_list, val, dprop, ray0, rdg,
                       B1, P2, b2, P3, b3, W4, b4);
    hipLaunchKernelGGL(refine_mfma, dim3(NRAY / 16), dim3(256), 0, stream,
                       val, dprop, ray0, rdg, W1, b1, P2, b2, P3, b3, W4, b4, out);
}

// Round 3
// 679.616 us; speedup vs baseline: 1.0676x; 1.0676x over previous
//
#include <hip/hip_runtime.h>
#include <math.h>

#define NRAY 8192
#define SSAMP 128
#define HD 256
#define AROW 264    // LDS row pitch in bf16
#define A1ROW 40    // layer1 A-tile pitch
#define FIXCAP 262144
#define FIXTHR 0.018f   // RNE 1-term tier: error margin ~= trunc tier @ 0.025

typedef short s16x8 __attribute__((ext_vector_type(8)));
typedef float f32x4 __attribute__((ext_vector_type(4)));

// ---------- bf16 helpers ----------
__device__ __forceinline__ unsigned short f2bf(float f) {      // RNE
    unsigned u = __float_as_uint(f);
    u += 0x7fffu + ((u >> 16) & 1u);
    return (unsigned short)(u >> 16);
}
__device__ __forceinline__ float bf2f(unsigned short s) {
    return __uint_as_float(((unsigned)s) << 16);
}
__device__ __forceinline__ void split2(float f, unsigned short& hi, unsigned short& lo) {
    unsigned u = __float_as_uint(f);
    hi = (unsigned short)(u >> 16);
    float r = f - __uint_as_float(u & 0xFFFF0000u);
    lo = f2bf(r);
}
// packed RNE f32->bf16x2 (gfx950 v_cvt_pk_bf16_f32): lo16 = bf16(a), hi16 = bf16(b)
__device__ __forceinline__ unsigned pack_bf16x2(float a, float b) {
    unsigned r;
    asm("v_cvt_pk_bf16_f32 %0, %1, %2" : "=v"(r) : "v"(a), "v"(b));
    return r;
}
// exact softplus (fixup / final tier)
__device__ __forceinline__ float softplus_fast(float x) {
    return fmaxf(x, 0.0f) + __logf(1.0f + __expf(-fabsf(x)));
}
// cheap softplus (1-term tier)
__device__ __forceinline__ float softplus_cheap(float x) {
    float m = __expf(-fabsf(x));
    float p = fmaf(m, fmaf(0.14258f, m, -0.44943f), 1.0f);
    return fmaxf(x, 0.0f) + m * p;
}
__device__ __forceinline__ float sigmoid_fast(float x) {
    return 1.0f / (1.0f + __expf(-x));
}

// ---------------- prep: pack W2/W3, pack layer1 B, cube intersection, zero counter ----------------
__global__ __launch_bounds__(256)
void prep_kernel(const float* __restrict__ W1, const float* __restrict__ b1,
                 const float* __restrict__ W2, const float* __restrict__ W3,
                 const float* __restrict__ ray0, const float* __restrict__ rdg,
                 unsigned short* __restrict__ P2, unsigned short* __restrict__ P3,
                 unsigned short* __restrict__ B1, float* __restrict__ rayinfo,
                 int* __restrict__ fix_cnt) {
    const int b = blockIdx.x, tid = threadIdx.x;
    if (b < 256) {
        int idx = b * 256 + tid;   // 0..65535
        int k = idx >> 8, n = idx & 255;
        int nt = n >> 4, kt = k >> 5, lq = (k >> 3) & 3, j = k & 7;
        int lane = (lq << 4) | (n & 15);
        size_t off = (size_t)((nt * 8 + kt) * 2) * 512 + (size_t)lane * 8 + j;
        float w = W2[idx];
        unsigned short hi = f2bf(w);
        P2[off] = hi; P2[off + 512] = f2bf(w - bf2f(hi));
        w = W3[idx];
        hi = f2bf(w);
        P3[off] = hi; P3[off + 512] = f2bf(w - bf2f(hi));
    } else if (b < 288) {
        int idx = (b - 256) * 256 + tid;   // 0..8191
        int w = idx & 511;
        int lane = w >> 3, j = w & 7;
        int k = ((lane >> 4) << 3) + j;
        int n = ((idx >> 9) << 4) + (lane & 15);
        unsigned short s = 0;
        if (k < 3) s = f2bf(W1[k * HD + n]);
        else if (k == 3) s = f2bf(b1[n]);
        else if (k < 7) s = f2bf(W1[(k - 4) * HD + n]);
        else if (k == 7) { unsigned short bh = f2bf(b1[n]); s = f2bf(b1[n] - bf2f(bh)); }
        else if (k < 11) { float wv = W1[(k - 8) * HD + n]; unsigned short wh = f2bf(wv); s = f2bf(wv - bf2f(wh)); }
        B1[idx] = s;
    } else {
        int r = (b - 288) * 256 + tid;     // 0..8191
        if (r == 0) *fix_cnt = 0;
        float o0 = ray0[3 * r], o1 = ray0[3 * r + 1], o2 = ray0[3 * r + 2];
        float v0 = rdg[3 * r], v1 = rdg[3 * r + 1], v2 = rdg[3 * r + 2];
        const float pd = 0.55f, lim = pd + 1e-6f;
        float di[6]; int insk[6]; int cnt = 0;
        for (int k = 0; k < 6; k++) {
            int a = k % 3;
            float pl = (k < 3) ? pd : -pd;
            float den = (a == 0) ? v0 : ((a == 1) ? v1 : v2);
            if (fabsf(den) < 1e-9f) den = 1e-9f;
            float oa = (a == 0) ? o0 : ((a == 1) ? o1 : o2);
            float dd = (pl - oa) / den;
            float px = o0 + dd * v0, py = o1 + dd * v1, pz = o2 + dd * v2;
            int ins = (fabsf(px) <= lim) && (fabsf(py) <= lim) && (fabsf(pz) <= lim);
            di[k] = dd; insk[k] = ins; cnt += ins;
        }
        float d0 = 0.f, sl = 2.4f;
        if (cnt == 2) {
            int k1 = -1, k2 = -1;
            for (int k = 0; k < 6; k++) if (insk[k]) { if (k1 < 0) k1 = k; else k2 = k; }
            float nrd = sqrtf(v0 * v0 + v1 * v1 + v2 * v2);
            float ax = di[k1] * v0, ay = di[k1] * v1, az = di[k1] * v2;
            float d1n = sqrtf(ax * ax + ay * ay + az * az) / nrd;
            float bx = di[k2] * v0, by = di[k2] * v1, bz = di[k2] * v2;
            float d2n = sqrtf(bx * bx + by * by + bz * bz) / nrd;
            d0 = fminf(d1n, d2n);
            sl = fmaxf(d1n, d2n) - d0;
        }
        float* ri = rayinfo + (size_t)r * 8;
        ri[0] = d0; ri[1] = sl;
        ri[2] = o0; ri[3] = o1; ri[4] = o2;
        ri[5] = v0; ri[6] = v1; ri[7] = v2;
    }
}

// ============ All GEMMs are operand-SWAPPED: D = W^T * Act^T ============
// C layout: col(lane&15)=sample, row((lane>>4)*4+reg)=channel -> each lane's 4 regs are
// 4 consecutive channels of one sample -> packed uint2 epilogue stores, float4 bias/W4.
// NT = number of 16-channel output chunks per wave (waves*NT must equal 16).

// ---------- layer1 GEMM: one K=32 tile, acc = B1^T @ A1^T (bias folded in) ----------
template<int MT, int NT>
__device__ __forceinline__ void gemm_l1(const unsigned short* A1,
                                        const unsigned short* __restrict__ B1,
                                        f32x4 acc[MT][NT], int lane, int ntbase) {
    const int r15 = lane & 15, q = lane >> 4;
    s16x8 wh[NT];
#pragma unroll
    for (int nt = 0; nt < NT; nt++)
        wh[nt] = *(((const s16x8*)B1) + (size_t)(ntbase + nt) * 64 + lane);
#pragma unroll
    for (int mt = 0; mt < MT; mt++) {
        s16x8 ah = *(const s16x8*)(A1 + (mt * 16 + r15) * A1ROW + q * 8);
#pragma unroll
        for (int nt = 0; nt < NT; nt++)
            acc[mt][nt] = __builtin_amdgcn_mfma_f32_16x16x32_bf16(wh[nt], ah, (f32x4){0.f,0.f,0.f,0.f}, 0, 0, 0);
    }
}

// ---------- 1-term bf16 GEMM: acc += Wh^T * Ah^T ----------
template<int MT, int NT>
__device__ __forceinline__ void gemm_1t(const unsigned short* Act,
                                        const unsigned short* __restrict__ Wp,
                                        f32x4 acc[MT][NT], int lane, int ntbase) {
#pragma unroll
    for (int mt = 0; mt < MT; mt++)
#pragma unroll
        for (int nt = 0; nt < NT; nt++) acc[mt][nt] = (f32x4){0.f, 0.f, 0.f, 0.f};
    const int r15 = lane & 15, q = lane >> 4;
#pragma unroll 2
    for (int kt = 0; kt < 8; kt++) {
        s16x8 wh[NT];
#pragma unroll
        for (int nt = 0; nt < NT; nt++) {
            const s16x8* wp = ((const s16x8*)Wp) + (size_t)((ntbase + nt) * 8 + kt) * 128 + lane;
            wh[nt] = wp[0];
        }
        const int kc = kt * 32 + q * 8;
#pragma unroll
        for (int mt = 0; mt < MT; mt++) {
            s16x8 ah = *(const s16x8*)(Act + (mt * 16 + r15) * AROW + kc);
#pragma unroll
            for (int nt = 0; nt < NT; nt++)
                acc[mt][nt] = __builtin_amdgcn_mfma_f32_16x16x32_bf16(wh[nt], ah, acc[mt][nt], 0, 0, 0);
        }
    }
}

// ---------- 3-term split GEMM (fixup tier): Wh*Ah + Wh*Al + Wl*Ah ----------
template<int MT, int NT>
__device__ __forceinline__ void gemm_3t(const unsigned short* Ahi, const unsigned short* Alo,
                                        const unsigned short* __restrict__ Wp,
                                        f32x4 acc[MT][NT], int lane, int ntbase) {
#pragma unroll
    for (int mt = 0; mt < MT; mt++)
#pragma unroll
        for (int nt = 0; nt < NT; nt++) acc[mt][nt] = (f32x4){0.f, 0.f, 0.f, 0.f};
    const int r15 = lane & 15, q = lane >> 4;
#pragma unroll 2
    for (int kt = 0; kt < 8; kt++) {
        s16x8 wh[NT], wl[NT];
#pragma unroll
        for (int nt = 0; nt < NT; nt++) {
            const s16x8* wp = ((const s16x8*)Wp) + (size_t)((ntbase + nt) * 8 + kt) * 128 + lane;
            wh[nt] = wp[0];
            wl[nt] = wp[64];
        }
        const int kc = kt * 32 + q * 8;
#pragma unroll
        for (int mt = 0; mt < MT; mt++) {
            s16x8 ah = *(const s16x8*)(Ahi + (mt * 16 + r15) * AROW + kc);
            s16x8 al = *(const s16x8*)(Alo + (mt * 16 + r15) * AROW + kc);
#pragma unroll
            for (int nt = 0; nt < NT; nt++) {
                acc[mt][nt] = __builtin_amdgcn_mfma_f32_16x16x32_bf16(wh[nt], ah, acc[mt][nt], 0, 0, 0);
                acc[mt][nt] = __builtin_amdgcn_mfma_f32_16x16x32_bf16(wl[nt], ah, acc[mt][nt], 0, 0, 0);
                acc[mt][nt] = __builtin_amdgcn_mfma_f32_16x16x32_bf16(wh[nt], al, acc[mt][nt], 0, 0, 0);
            }
        }
    }
}

// dual (value + tangent) 3-term variant — final tier
template<int MT, int NT>
__device__ __forceinline__ void gemm_dual(const unsigned short* Avh, const unsigned short* Avl,
                                          const unsigned short* Ath, const unsigned short* Atl,
                                          const unsigned short* __restrict__ Wp,
                                          f32x4 av[MT][NT], f32x4 at[MT][NT], int lane, int ntbase) {
#pragma unroll
    for (int mt = 0; mt < MT; mt++)
#pragma unroll
        for (int nt = 0; nt < NT; nt++) {
            av[mt][nt] = (f32x4){0.f, 0.f, 0.f, 0.f};
            at[mt][nt] = (f32x4){0.f, 0.f, 0.f, 0.f};
        }
    const int r15 = lane & 15, q = lane >> 4;
#pragma unroll 2
    for (int kt = 0; kt < 8; kt++) {
        s16x8 wh[NT], wl[NT];
#pragma unroll
        for (int nt = 0; nt < NT; nt++) {
            const s16x8* wp = ((const s16x8*)Wp) + (size_t)((ntbase + nt) * 8 + kt) * 128 + lane;
            wh[nt] = wp[0];
            wl[nt] = wp[64];
        }
        const int kc = kt * 32 + q * 8;
#pragma unroll
        for (int mt = 0; mt < MT; mt++) {
            s16x8 avhf = *(const s16x8*)(Avh + (mt * 16 + r15) * AROW + kc);
            s16x8 avlf = *(const s16x8*)(Avl + (mt * 16 + r15) * AROW + kc);
            s16x8 athf = *(const s16x8*)(Ath + (mt * 16 + r15) * AROW + kc);
            s16x8 atlf = *(const s16x8*)(Atl + (mt * 16 + r15) * AROW + kc);
#pragma unroll
            for (int nt = 0; nt < NT; nt++) {
                av[mt][nt] = __builtin_amdgcn_mfma_f32_16x16x32_bf16(wh[nt], avhf, av[mt][nt], 0, 0, 0);
                av[mt][nt] = __builtin_amdgcn_mfma_f32_16x16x32_bf16(wl[nt], avhf, av[mt][nt], 0, 0, 0);
                av[mt][nt] = __builtin_amdgcn_mfma_f32_16x16x32_bf16(wh[nt], avlf, av[mt][nt], 0, 0, 0);
                at[mt][nt] = __builtin_amdgcn_mfma_f32_16x16x32_bf16(wh[nt], athf, at[mt][nt], 0, 0, 0);
                at[mt][nt] = __builtin_amdgcn_mfma_f32_16x16x32_bf16(wl[nt], athf, at[mt][nt], 0, 0, 0);
                at[mt][nt] = __builtin_amdgcn_mfma_f32_16x16x32_bf16(wh[nt], atlf, at[mt][nt], 0, 0, 0);
            }
        }
    }
}

// epilogue (layer1, bias folded): cheap softplus + packed RNE store (transposed layout)
template<int MT, int NT>
__device__ __forceinline__ void epi_l1(f32x4 acc[MT][NT], unsigned short* Ahi, int lane, int wn0) {
    const int r15 = lane & 15, q = lane >> 4;
#pragma unroll
    for (int mt = 0; mt < MT; mt++) {
        unsigned short* rowp = Ahi + (mt * 16 + r15) * AROW + wn0 + q * 4;
#pragma unroll
        for (int nt = 0; nt < NT; nt++) {
            float h0 = softplus_cheap(acc[mt][nt][0]);
            float h1 = softplus_cheap(acc[mt][nt][1]);
            float h2 = softplus_cheap(acc[mt][nt][2]);
            float h3 = softplus_cheap(acc[mt][nt][3]);
            *reinterpret_cast<uint2*>(rowp + nt * 16) =
                make_uint2(pack_bf16x2(h0, h1), pack_bf16x2(h2, h3));
        }
    }
}

// epilogue (layer1, bias folded): exact softplus + hi/lo split (fixup tier)
template<int MT, int NT>
__device__ __forceinline__ void epi_l1_sp(f32x4 acc[MT][NT], unsigned short* Ahi, unsigned short* Alo,
                                          int lane, int wn0) {
    const int r15 = lane & 15, q = lane >> 4;
#pragma unroll
    for (int mt = 0; mt < MT; mt++) {
        const int rowoff = (mt * 16 + r15) * AROW + wn0 + q * 4;
#pragma unroll
        for (int nt = 0; nt < NT; nt++) {
            float h0 = softplus_fast(acc[mt][nt][0]);
            float h1 = softplus_fast(acc[mt][nt][1]);
            float h2 = softplus_fast(acc[mt][nt][2]);
            float h3 = softplus_fast(acc[mt][nt][3]);
            unsigned x0 = pack_bf16x2(h0, h1), x1 = pack_bf16x2(h2, h3);
            float l0 = h0 - __uint_as_float(x0 << 16);
            float l1 = h1 - __uint_as_float(x0 & 0xFFFF0000u);
            float l2 = h2 - __uint_as_float(x1 << 16);
            float l3 = h3 - __uint_as_float(x1 & 0xFFFF0000u);
            *reinterpret_cast<uint2*>(Ahi + rowoff + nt * 16) = make_uint2(x0, x1);
            *reinterpret_cast<uint2*>(Alo + rowoff + nt * 16) =
                make_uint2(pack_bf16x2(l0, l1), pack_bf16x2(l2, l3));
        }
    }
}

// epilogue (1-term): cheap softplus + packed RNE store
template<int MT, int NT>
__device__ __forceinline__ void epi_hidden_1t(f32x4 acc[MT][NT], const float* __restrict__ b,
                                              unsigned short* Ahi, int lane, int wn0) {
    const int r15 = lane & 15, q = lane >> 4;
    f32x4 bb[NT];
#pragma unroll
    for (int nt = 0; nt < NT; nt++) bb[nt] = *(const f32x4*)(b + wn0 + nt * 16 + q * 4);
#pragma unroll
    for (int mt = 0; mt < MT; mt++) {
        unsigned short* rowp = Ahi + (mt * 16 + r15) * AROW + wn0 + q * 4;
#pragma unroll
        for (int nt = 0; nt < NT; nt++) {
            float h0 = softplus_cheap(acc[mt][nt][0] + bb[nt][0]);
            float h1 = softplus_cheap(acc[mt][nt][1] + bb[nt][1]);
            float h2 = softplus_cheap(acc[mt][nt][2] + bb[nt][2]);
            float h3 = softplus_cheap(acc[mt][nt][3] + bb[nt][3]);
            *reinterpret_cast<uint2*>(rowp + nt * 16) =
                make_uint2(pack_bf16x2(h0, h1), pack_bf16x2(h2, h3));
        }
    }
}

// epilogue (split hi/lo, fixup tier) — exact softplus
template<int MT, int NT>
__device__ __forceinline__ void epi_hidden_sp(f32x4 acc[MT][NT], const float* __restrict__ b,
                                              unsigned short* Ahi, unsigned short* Alo,
                                              int lane, int wn0) {
    const int r15 = lane & 15, q = lane >> 4;
    f32x4 bb[NT];
#pragma unroll
    for (int nt = 0; nt < NT; nt++) bb[nt] = *(const f32x4*)(b + wn0 + nt * 16 + q * 4);
#pragma unroll
    for (int mt = 0; mt < MT; mt++) {
        const int rowoff = (mt * 16 + r15) * AROW + wn0 + q * 4;
#pragma unroll
        for (int nt = 0; nt < NT; nt++) {
            float h0 = softplus_fast(acc[mt][nt][0] + bb[nt][0]);
            float h1 = softplus_fast(acc[mt][nt][1] + bb[nt][1]);
            float h2 = softplus_fast(acc[mt][nt][2] + bb[nt][2]);
            float h3 = softplus_fast(acc[mt][nt][3] + bb[nt][3]);
            unsigned x0 = pack_bf16x2(h0, h1), x1 = pack_bf16x2(h2, h3);
            float l0 = h0 - __uint_as_float(x0 << 16);
            float l1 = h1 - __uint_as_float(x0 & 0xFFFF0000u);
            float l2 = h2 - __uint_as_float(x1 << 16);
            float l3 = h3 - __uint_as_float(x1 & 0xFFFF0000u);
            *reinterpret_cast<uint2*>(Ahi + rowoff + nt * 16) = make_uint2(x0, x1);
            *reinterpret_cast<uint2*>(Alo + rowoff + nt * 16) =
                make_uint2(pack_bf16x2(l0, l1), pack_bf16x2(l2, l3));
        }
    }
}

template<int MT, int NT>
__device__ __forceinline__ void epi_dual(f32x4 av[MT][NT], f32x4 at[MT][NT], const float* __restrict__ b,
                                         unsigned short* Avh, unsigned short* Avl,
                                         unsigned short* Ath, unsigned short* Atl,
                                         int lane, int wn0) {
    const int r15 = lane & 15, q = lane >> 4;
    f32x4 bb[NT];
#pragma unroll
    for (int nt = 0; nt < NT; nt++) bb[nt] = *(const f32x4*)(b + wn0 + nt * 16 + q * 4);
#pragma unroll
    for (int mt = 0; mt < MT; mt++) {
        const int rowoff = (mt * 16 + r15) * AROW + wn0 + q * 4;
#pragma unroll
        for (int nt = 0; nt < NT; nt++) {
            float h[4], g[4];
#pragma unroll
            for (int r = 0; r < 4; r++) {
                float z = av[mt][nt][r] + bb[nt][r];
                h[r] = softplus_fast(z);
                g[r] = sigmoid_fast(z) * at[mt][nt][r];
            }
            unsigned x0 = pack_bf16x2(h[0], h[1]), x1 = pack_bf16x2(h[2], h[3]);
            float l0 = h[0] - __uint_as_float(x0 << 16);
            float l1 = h[1] - __uint_as_float(x0 & 0xFFFF0000u);
            float l2 = h[2] - __uint_as_float(x1 << 16);
            float l3 = h[3] - __uint_as_float(x1 & 0xFFFF0000u);
            *reinterpret_cast<uint2*>(Avh + rowoff + nt * 16) = make_uint2(x0, x1);
            *reinterpret_cast<uint2*>(Avl + rowoff + nt * 16) =
                make_uint2(pack_bf16x2(l0, l1), pack_bf16x2(l2, l3));
            x0 = pack_bf16x2(g[0], g[1]); x1 = pack_bf16x2(g[2], g[3]);
            l0 = g[0] - __uint_as_float(x0 << 16);
            l1 = g[1] - __uint_as_float(x0 & 0xFFFF0000u);
            l2 = g[2] - __uint_as_float(x1 << 16);
            l3 = g[3] - __uint_as_float(x1 & 0xFFFF0000u);
            *reinterpret_cast<uint2*>(Ath + rowoff + nt * 16) = make_uint2(x0, x1);
            *reinterpret_cast<uint2*>(Atl + rowoff + nt * 16) =
                make_uint2(pack_bf16x2(l0, l1), pack_bf16x2(l2, l3));
        }
    }
}

// layer3 activation + W4 dot (transposed): lane-local dot over 4*NT channels, 2 shuffles
template<int MT, int NT, bool CH>
__device__ __forceinline__ void l4_reduce(f32x4 acc[MT][NT], const float* __restrict__ b3,
                                          const float* __restrict__ W4,
                                          float* partial, int lane, int wn0) {
    const int r15 = lane & 15, q = lane >> 4;
    f32x4 w4v[NT], b3v[NT];
#pragma unroll
    for (int nt = 0; nt < NT; nt++) {
        w4v[nt] = *(const f32x4*)(W4 + wn0 + nt * 16 + q * 4);
        b3v[nt] = *(const f32x4*)(b3 + wn0 + nt * 16 + q * 4);
    }
#pragma unroll
    for (int mt = 0; mt < MT; mt++) {
        float p = 0.f;
#pragma unroll
        for (int nt = 0; nt < NT; nt++)
#pragma unroll
            for (int r = 0; r < 4; r++) {
                float z = acc[mt][nt][r] + b3v[nt][r];
                float h = CH ? softplus_cheap(z) : softplus_fast(z);
                p = fmaf(h, w4v[nt][r], p);
            }
        p += __shfl_xor(p, 16, 64);
        p += __shfl_xor(p, 32, 64);
        if (q == 0) partial[mt * 16 + r15] = p;
    }
}

template<int MT, int NT>
__device__ __forceinline__ void l4_reduce_dual(f32x4 av[MT][NT], f32x4 at[MT][NT],
                                               const float* __restrict__ b3, const float* __restrict__ W4,
                                               float* pv, float* pt, int lane, int wn0) {
    const int r15 = lane & 15, q = lane >> 4;
    f32x4 w4v[NT], b3v[NT];
#pragma unroll
    for (int nt = 0; nt < NT; nt++) {
        w4v[nt] = *(const f32x4*)(W4 + wn0 + nt * 16 + q * 4);
        b3v[nt] = *(const f32x4*)(b3 + wn0 + nt * 16 + q * 4);
    }
#pragma unroll
    for (int mt = 0; mt < MT; mt++) {
        float sv = 0.f, st = 0.f;
#pragma unroll
        for (int nt = 0; nt < NT; nt++)
#pragma unroll
            for (int r = 0; r < 4; r++) {
                float z = av[mt][nt][r] + b3v[nt][r];
                sv = fmaf(softplus_fast(z), w4v[nt][r], sv);
                st = fmaf(sigmoid_fast(z) * at[mt][nt][r], w4v[nt][r], st);
            }
        sv += __shfl_xor(sv, 16, 64);
        sv += __shfl_xor(sv, 32, 64);
        st += __shfl_xor(st, 16, 64);
        st += __shfl_xor(st, 32, 64);
        if (q == 0) {
            pv[mt * 16 + r15] = sv;
            pt[mt * 16 + r15] = st;
        }
    }
}

// ---------------- coarse: block = whole ray, 128 samples, 8 waves (MT=8, NT=2) ----------------
// Whole-ray blocks halve per-sample L2 weight traffic, barrier count, and LDS act
// re-reads vs 64-sample blocks: same 256KB weight reads + 4 syncs now cover 128 samples.
// LDS 76KB -> 2 blocks/CU; __launch_bounds__(512,4) pins VGPR<=128 so both stay resident.
__global__ __launch_bounds__(512, 4)
void coarse_mfma(const float* __restrict__ rayinfo,
                 const unsigned short* __restrict__ B1,
                 const unsigned short* __restrict__ P2, const float* __restrict__ b2,
                 const unsigned short* __restrict__ P3, const float* __restrict__ b3,
                 const float* __restrict__ W4, const float* __restrict__ b4,
                 float* __restrict__ val_out, float* __restrict__ dprop_out,
                 int* __restrict__ fix_cnt, int* __restrict__ fix_list) {
    __shared__ __align__(16) unsigned short Ahi[128 * AROW];
    __shared__ __align__(16) unsigned short A1[128 * A1ROW];
    float* partial = (float*)A1;    // 8*128 floats = 4KB <= 10KB, A1 dead after gemm_l1
    const int tid = threadIdx.x;
    const int lane = tid & 63, wave = tid >> 6;   // wave 0..7
    const int r = blockIdx.x;

    if (tid < 128) {
        const float* ri = rayinfo + (size_t)r * 8;
        const int s = tid;
        float t = (float)s * (1.0f / 127.0f);
        float d = fmaf(t, ri[1], ri[0]);
        dprop_out[r * SSAMP + s] = d;
        float px = fmaf(d, ri[5], ri[2]);
        float py = fmaf(d, ri[6], ri[3]);
        float pz = fmaf(d, ri[7], ri[4]);
        unsigned short hx, lx, hy, ly, hz, lz;
        split2(px, hx, lx); split2(py, hy, ly); split2(pz, hz, lz);
        unsigned short* row = A1 + tid * A1ROW;
        row[0] = hx; row[1] = hy; row[2] = hz; row[3] = 0x3F80u;
        row[4] = lx; row[5] = ly; row[6] = lz; row[7] = 0x3F80u;
        row[8] = hx; row[9] = hy; row[10] = hz;
#pragma unroll
        for (int c = 11; c < 32; c++) row[c] = 0;
    }
    __syncthreads();
    f32x4 acc[8][2];
    gemm_l1<8, 2>(A1, B1, acc, lane, wave * 2);
    epi_l1<8, 2>(acc, Ahi, lane, wave * 32);
    __syncthreads();
    gemm_1t<8, 2>(Ahi, P2, acc, lane, wave * 2);
    __syncthreads();
    epi_hidden_1t<8, 2>(acc, b2, Ahi, lane, wave * 32);
    __syncthreads();
    gemm_1t<8, 2>(Ahi, P3, acc, lane, wave * 2);
    l4_reduce<8, 2, true>(acc, b3, W4, &partial[wave * 128], lane, wave * 32);
    __syncthreads();
    if (tid < 128) {
        float v = b4[0];
#pragma unroll
        for (int w = 0; w < 8; w++) v += partial[w * 128 + tid];
        int idx = r * SSAMP + tid;
        val_out[idx] = v;
        if (fabsf(v) < FIXTHR) {
            int pos = atomicAdd(fix_cnt, 1);
            if (pos < FIXCAP) fix_list[pos] = idx;
        }
    }
}

// ---------------- fixup (32-sample 3-term MFMA batches, MFMA layer1, 4 blocks/CU) ----------------
__global__ __launch_bounds__(256, 4)
void fixup3_mfma(const int* __restrict__ counter, const int* __restrict__ list,
                 float* __restrict__ val, const float* __restrict__ dprop,
                 const float* __restrict__ ray0, const float* __restrict__ rdg,
                 const unsigned short* __restrict__ B1,
                 const unsigned short* __restrict__ P2, const float* __restrict__ b2,
                 const unsigned short* __restrict__ P3, const float* __restrict__ b3,
                 const float* __restrict__ W4, const float* __restrict__ b4) {
    __shared__ __align__(16) unsigned short Ahi[32 * AROW];
    __shared__ __align__(16) unsigned short Alo[32 * AROW];
    __shared__ __align__(16) unsigned short A1[32 * A1ROW];
    __shared__ float partial[4][32];
    __shared__ int bidxs[32];
    const int cnt = min(*counter, FIXCAP);
    const int base = blockIdx.x * 32;
    if (base >= cnt) return;
    const int tid = threadIdx.x;
    const int lane = tid & 63, wave = tid >> 6;
    if (tid < 32) {
        const int i = min(base + tid, cnt - 1);   // tail clamp: duplicates write same value
        const int bidx = list[i];
        bidxs[tid] = bidx;
        const int rr = bidx >> 7;                 // r-major: idx = r*SSAMP + s
        float d = dprop[bidx];
        float px = ray0[3 * rr] + d * rdg[3 * rr];
        float py = ray0[3 * rr + 1] + d * rdg[3 * rr + 1];
        float pz = ray0[3 * rr + 2] + d * rdg[3 * rr + 2];
        unsigned short hx, lx, hy, ly, hz, lz;
        split2(px, hx, lx); split2(py, hy, ly); split2(pz, hz, lz);
        unsigned short* row = A1 + tid * A1ROW;
        row[0] = hx; row[1] = hy; row[2] = hz; row[3] = 0x3F80u;
        row[4] = lx; row[5] = ly; row[6] = lz; row[7] = 0x3F80u;
        row[8] = hx; row[9] = hy; row[10] = hz;
#pragma unroll
        for (int c = 11; c < 32; c++) row[c] = 0;
    }
    __syncthreads();
    f32x4 acc[2][4];
    gemm_l1<2, 4>(A1, B1, acc, lane, wave * 4);
    epi_l1_sp<2, 4>(acc, Ahi, Alo, lane, wave * 64);
    __syncthreads();
    gemm_3t<2, 4>(Ahi, Alo, P2, acc, lane, wave * 4);
    __syncthreads();
    epi_hidden_sp<2, 4>(acc, b2, Ahi, Alo, lane, wave * 64);
    __syncthreads();
    gemm_3t<2, 4>(Ahi, Alo, P3, acc, lane, wave * 4);
    l4_reduce<2, 4, false>(acc, b3, W4, &partial[wave][0], lane, wave * 64);
    __syncthreads();
    if (tid < 32) {
        float v = partial[0][tid] + partial[1][tid] + partial[2][tid] + partial[3][tid] + b4[0];
        val[bidxs[tid]] = v;
    }
}

// ---------------- refine: scan + 8-iter secant + final dual, all in one (16 rays/block) ----------------
__global__ __launch_bounds__(256, 4)
void refine_mfma(const float* __restrict__ val, const float* __restrict__ dprop,
                 const float* __restrict__ ray0, const float* __restrict__ rdg,
                 const float* __restrict__ W1, const float* __restrict__ b1,
                 const unsigned short* __restrict__ P2, const float* __restrict__ b2,
                 const unsigned short* __restrict__ P3, const float* __restrict__ b3,
                 const float* __restrict__ W4, const float* __restrict__ b4,
                 float* __restrict__ out) {
    __shared__ __align__(16) unsigned short Avh[16 * AROW];
    __shared__ __align__(16) unsigned short Avl[16 * AROW];
    __shared__ __align__(16) unsigned short Ath[16 * AROW];
    __shared__ __align__(16) unsigned short Atl[16 * AROW];
    __shared__ float partial[4][16], ptan[4][16];
    __shared__ float dl[16], fl[16], dh[16], fh[16], dps[16];
    __shared__ int mks[16];
    unsigned short* Ahi = Avh;   // secant reuses plane 0
    const int tid = threadIdx.x;
    const int lane = tid & 63, wave = tid >> 6;
    const int r0 = blockIdx.x * 16;

    // ---- scan: wave w handles rays r0+w*4 .. +3 ----
    for (int i = 0; i < 4; i++) {
        const int r = r0 + wave * 4 + i;
        const float2 v = *(const float2*)(val + (size_t)r * SSAMP + lane * 2);
        const float2 dd = *(const float2*)(dprop + (size_t)r * SSAMP + lane * 2);
        float vnext = __shfl_down(v.x, 1, 64);
        const int s0 = lane * 2, s1 = s0 + 1;
        float pr0 = v.x * v.y;
        int sg0 = (pr0 > 0.f) ? 1 : ((pr0 < 0.f) ? -1 : 0);
        int k0 = (sg0 * (SSAMP - s0) + 129) * 256 + s0;
        int k1;
        if (lane == 63) {
            k1 = (1 + 129) * 256 + 127;          // appended cost[127] = 1
        } else {
            float pr1 = v.y * vnext;
            int sg1 = (pr1 > 0.f) ? 1 : ((pr1 < 0.f) ? -1 : 0);
            k1 = (sg1 * (SSAMP - s1) + 129) * 256 + s1;
        }
        int k = min(k0, k1);
#pragma unroll
        for (int m = 1; m < 64; m <<= 1) k = min(k, __shfl_xor(k, m, 64));
        int bidx = k & 255;
        int cmin = (k >> 8) - 129;
        int idxh = min(bidx + 1, SSAMP - 1);
        int ow = bidx >> 1, oh = idxh >> 1;
        float fa = __shfl(v.x, ow, 64), fb = __shfl(v.y, ow, 64);
        float da = __shfl(dd.x, ow, 64), db = __shfl(dd.y, ow, 64);
        float fa2 = __shfl(v.x, oh, 64), fb2 = __shfl(v.y, oh, 64);
        float da2 = __shfl(dd.x, oh, 64), db2 = __shfl(dd.y, oh, 64);
        float v0 = __shfl(v.x, 0, 64);
        if (lane == 0) {
            float f_low = (bidx & 1) ? fb : fa;
            float d_low = (bidx & 1) ? db : da;
            float f_high = (idxh & 1) ? fb2 : fa2;
            float d_high = (idxh & 1) ? db2 : da2;
            int sl = wave * 4 + i;
            mks[sl] = (cmin < 0) && (f_low < 0.f) && (v0 < 0.f);
            float den = f_high - f_low;
            if (fabsf(den) < 1e-12f) den = 1e-12f;
            dl[sl] = d_low; fl[sl] = f_low; dh[sl] = d_high; fh[sl] = f_high;
            dps[sl] = -f_low * (d_high - d_low) / den + d_low;
        }
    }
    __syncthreads();
    // ---- 8 secant iterations (1-term, cheap softplus) ----
    for (int it = 0; it < 8; it++) {
        {
            const int pt = tid >> 4, jb = (tid & 15) << 4;
            const int rr = r0 + pt;
            float d = dps[pt];
            float px = ray0[3 * rr] + d * rdg[3 * rr];
            float py = ray0[3 * rr + 1] + d * rdg[3 * rr + 1];
            float pz = ray0[3 * rr + 2] + d * rdg[3 * rr + 2];
            for (int j = jb; j < jb + 16; j += 4) {
                float4 wa = *(const float4*)(W1 + j);
                float4 wb = *(const float4*)(W1 + 256 + j);
                float4 wc = *(const float4*)(W1 + 512 + j);
                float4 bb = *(const float4*)(b1 + j);
                float z[4];
                z[0] = fmaf(px, wa.x, fmaf(py, wb.x, fmaf(pz, wc.x, bb.x)));
                z[1] = fmaf(px, wa.y, fmaf(py, wb.y, fmaf(pz, wc.y, bb.y)));
                z[2] = fmaf(px, wa.z, fmaf(py, wb.z, fmaf(pz, wc.z, bb.z)));
                z[3] = fmaf(px, wa.w, fmaf(py, wb.w, fmaf(pz, wc.w, bb.w)));
                *reinterpret_cast<uint2*>(&Ahi[pt * AROW + j]) =
                    make_uint2(pack_bf16x2(softplus_cheap(z[0]), softplus_cheap(z[1])),
                               pack_bf16x2(softplus_cheap(z[2]), softplus_cheap(z[3])));
            }
        }
        __syncthreads();
        f32x4 acc[1][4];
        gemm_1t<1, 4>(Ahi, P2, acc, lane, wave * 4);
        __syncthreads();
        epi_hidden_1t<1, 4>(acc, b2, Ahi, lane, wave * 64);
        __syncthreads();
        gemm_1t<1, 4>(Ahi, P3, acc, lane, wave * 4);
        l4_reduce<1, 4, true>(acc, b3, W4, &partial[wave][0], lane, wave * 64);
        __syncthreads();
        if (tid < 16) {
            float fm = partial[0][tid] + partial[1][tid] + partial[2][tid] + partial[3][tid] + b4[0];
            float dpv = dps[tid];
            float dlv = dl[tid], flv = fl[tid], dhv = dh[tid], fhv = fh[tid];
            if (fm < 0.f) { dlv = dpv; flv = fm; } else { dhv = dpv; fhv = fm; }
            float den = fhv - flv;
            if (fabsf(den) < 1e-12f) den = 1e-12f;
            dps[tid] = -flv * (dhv - dlv) / den + dlv;
            dl[tid] = dlv; fl[tid] = flv; dh[tid] = dhv; fh[tid] = fhv;
        }
        __syncthreads();
    }
    // ---- final: dual-number 3-term eval + implicit correction ----
    {
        const int pt = tid >> 4, jb = (tid & 15) << 4;
        const int rr = r0 + pt;
        float d = dps[pt];
        float v0 = rdg[3 * rr], v1 = rdg[3 * rr + 1], v2 = rdg[3 * rr + 2];
        float px = ray0[3 * rr] + d * v0;
        float py = ray0[3 * rr + 1] + d * v1;
        float pz = ray0[3 * rr + 2] + d * v2;
        for (int j = jb; j < jb + 16; j += 4) {
            float4 wa = *(const float4*)(W1 + j);
            float4 wb = *(const float4*)(W1 + 256 + j);
            float4 wc = *(const float4*)(W1 + 512 + j);
            float4 bb = *(const float4*)(b1 + j);
            float z[4], zt[4], h[4], g[4];
            z[0] = fmaf(px, wa.x, fmaf(py, wb.x, fmaf(pz, wc.x, bb.x)));
            z[1] = fmaf(px, wa.y, fmaf(py, wb.y, fmaf(pz, wc.y, bb.y)));
            z[2] = fmaf(px, wa.z, fmaf(py, wb.z, fmaf(pz, wc.z, bb.z)));
            z[3] = fmaf(px, wa.w, fmaf(py, wb.w, fmaf(pz, wc.w, bb.w)));
            zt[0] = fmaf(v0, wa.x, fmaf(v1, wb.x, v2 * wc.x));
            zt[1] = fmaf(v0, wa.y, fmaf(v1, wb.y, v2 * wc.y));
            zt[2] = fmaf(v0, wa.z, fmaf(v1, wb.z, v2 * wc.z));
            zt[3] = fmaf(v0, wa.w, fmaf(v1, wb.w, v2 * wc.w));
#pragma unroll
            for (int i = 0; i < 4; i++) {
                h[i] = softplus_fast(z[i]);
                g[i] = sigmoid_fast(z[i]) * zt[i];
            }
            unsigned x0 = pack_bf16x2(h[0], h[1]), x1 = pack_bf16x2(h[2], h[3]);
            float l0 = h[0] - __uint_as_float(x0 << 16);
            float l1 = h[1] - __uint_as_float(x0 & 0xFFFF0000u);
            float l2 = h[2] - __uint_as_float(x1 << 16);
            float l3 = h[3] - __uint_as_float(x1 & 0xFFFF0000u);
            *reinterpret_cast<uint2*>(&Avh[pt * AROW + j]) = make_uint2(x0, x1);
            *reinterpret_cast<uint2*>(&Avl[pt * AROW + j]) =
                make_uint2(pack_bf16x2(l0, l1), pack_bf16x2(l2, l3));
            x0 = pack_bf16x2(g[0], g[1]); x1 = pack_bf16x2(g[2], g[3]);
            l0 = g[0] - __uint_as_float(x0 << 16);
            l1 = g[1] - __uint_as_float(x0 & 0xFFFF0000u);
            l2 = g[2] - __uint_as_float(x1 << 16);
            l3 = g[3] - __uint_as_float(x1 & 0xFFFF0000u);
            *reinterpret_cast<uint2*>(&Ath[pt * AROW + j]) = make_uint2(x0, x1);
            *reinterpret_cast<uint2*>(&Atl[pt * AROW + j]) =
                make_uint2(pack_bf16x2(l0, l1), pack_bf16x2(l2, l3));
        }
    }
    __syncthreads();
    f32x4 av[1][4], at[1][4];
    gemm_dual<1, 4>(Avh, Avl, Ath, Atl, P2, av, at, lane, wave * 4);
    __syncthreads();
    epi_dual<1, 4>(av, at, b2, Avh, Avl, Ath, Atl, lane, wave * 64);
    __syncthreads();
    gemm_dual<1, 4>(Avh, Avl, Ath, Atl, P3, av, at, lane, wave * 4);
    l4_reduce_dual<1, 4>(av, at, b3, W4, &partial[wave][0], &ptan[wave][0], lane, wave * 64);
    __syncthreads();
    if (tid < 16) {
        float f = partial[0][tid] + partial[1][tid] + partial[2][tid] + partial[3][tid] + b4[0];
        float ft = ptan[0][tid] + ptan[1][tid] + ptan[2][tid] + ptan[3][tid];
        if (fabsf(ft) < 1e-6f) ft = (ft < 0.f) ? -1e-6f : 1e-6f;
        float dres = dps[tid] - f / ft;
        out[r0 + tid] = mks[tid] ? dres : 0.0f;
    }
}

extern "C" void kernel_launch(void* const* d_in, const int* in_sizes, int n_in,
                              void* d_out, int out_size, void* d_ws, size_t ws_size,
                              hipStream_t stream) {
    const float* ray0 = (const float*)d_in[0];
    const float* rdg  = (const float*)d_in[1];
    const float* W1 = (const float*)d_in[2];
    const float* b1 = (const float*)d_in[3];
    const float* W2 = (const float*)d_in[4];
    const float* b2 = (const float*)d_in[5];
    const float* W3 = (const float*)d_in[6];
    const float* b3 = (const float*)d_in[7];
    const float* W4 = (const float*)d_in[8];
    const float* b4 = (const float*)d_in[9];
    float* out = (float*)d_out;

    float* ws = (float*)d_ws;
    float* val    = ws;                                 // SSAMP*NRAY, r-major [r][s]
    float* dprop  = ws + (size_t)SSAMP * NRAY;          // r-major [r][s]
    unsigned short* P2 = (unsigned short*)(ws + (size_t)2 * SSAMP * NRAY);
    unsigned short* P3 = P2 + 131072;
    unsigned short* B1 = P3 + 131072;       // 8192 shorts
    float* rayinfo = (float*)(B1 + 8192);   // NRAY*8 floats
    int* fix_cnt  = (int*)(rayinfo + (size_t)NRAY * 8);
    int* fix_list = fix_cnt + 64;           // FIXCAP ints

    hipLaunchKernelGGL(prep_kernel, dim3(320), dim3(256), 0, stream,
                       W1, b1, W2, W3, ray0, rdg, P2, P3, B1, rayinfo, fix_cnt);
    hipLaunchKernelGGL(coarse_mfma, dim3(NRAY), dim3(512), 0, stream,
                       rayinfo, B1, P2, b2, P3, b3, W4, b4, val, dprop, fix_cnt, fix_list);
    hipLaunchKernelGGL(fixup3_mfma, dim3(FIXCAP / 32), dim3(256), 0, stream,
                       fix_cnt, fix_list, val, dprop, ray0, rdg,
                       B1, P2, b2, P3, b3, W4, b4);
    hipLaunchKernelGGL(refine_mfma, dim3(NRAY / 16), dim3(256), 0, stream,
                       val, dprop, ray0, rdg, W1, b1, P2, b2, P3, b3, W4, b4, out);
}